// Round 10
// baseline (196.943 us; speedup 1.0000x reference)
//
#include <hip/hip_runtime.h>
#include <math.h>

#define B_     2
#define N_     6890
#define NF_    2000
#define NFP_   2048     // padded triangles: 16 chunks x 128
#define NPT_   6912     // padded points: 27*256
#define OPP7_  7168     // padded opposite cloud: 7 chunks x 1024
#define TCG_   16       // tri chunks (128 tris each, 2 recs/lane)
#define OCG_   7        // opp chunks (1024 recs each, 16 recs/lane)
#define NTILE_ (4 * (TCG_ + OCG_) * 27)   // 2484 logical tiles (23-interleaved)
#define GRID_  2048                        // persistent

// ---------------------------------------------------------------------------
// atan2(y,x)/(2*pi): branchless octant reduction, single rcp, scale folded in.
// ---------------------------------------------------------------------------
__device__ __forceinline__ float atan2_o2pi(float y, float x) {
    float ax = __builtin_fabsf(x);
    float ay = __builtin_fabsf(y);
    float mx = fmaxf(ax, ay);
    float mn = fminf(ax, ay);
    bool  big = mn > 0.41421356f * mx;
    float num = big ? (mn - mx) : mn;
    float den = big ? (mn + mx) : mx;
    float t   = num * __builtin_amdgcn_rcpf(den);
    float z   = t * t;
    float p   = fmaf(fmaf(fmaf(1.2817932e-2f, z, -2.2087019e-2f), z,
                          3.1795514e-2f), z, -5.3051037e-2f);   // coeffs / 2pi
    float r   = fmaf(t, fmaf(z, p, 0.15915494309f), big ? 0.125f : 0.0f);
    r = (ay > ax)  ? 0.25f - r : r;
    r = (x < 0.0f) ? 0.5f  - r : r;
    return copysignf(r, y);
}

// ---------------------------------------------------------------------------
// prep (layouts unchanged):
//  pw[b][n] = (x,y,z,|p|^2)        pad zeros              [B][NPT_]
//  st[b][n] = (-2x,-2y,-2z,|o|^2)  pad (0,0,0,1e30)       [B][OPP7_]
//  tbl[b][f][20] = [A,B,C, -S, det0, na,nb,nc, qab,qbc,qca, 0]
// ---------------------------------------------------------------------------
__global__ void prep_kernel(const float* __restrict__ v1, const float* __restrict__ v2,
                            const int* __restrict__ faces,
                            float4* __restrict__ pw1, float4* __restrict__ pw2,
                            float4* __restrict__ st1, float4* __restrict__ st2,
                            float* __restrict__ tbl1, float* __restrict__ tbl2) {
    int tid = blockIdx.x * 256 + threadIdx.x;

    if (tid < B_ * NPT_) {
        int b = tid / NPT_, n = tid - b * NPT_;
        float4 q1 = make_float4(0.f, 0.f, 0.f, 0.f), q2 = q1;
        if (n < N_) {
            float x1 = v1[(b*N_+n)*3+0], y1 = v1[(b*N_+n)*3+1], z1 = v1[(b*N_+n)*3+2];
            float x2 = v2[(b*N_+n)*3+0], y2 = v2[(b*N_+n)*3+1], z2 = v2[(b*N_+n)*3+2];
            q1 = make_float4(x1, y1, z1, fmaf(x1,x1, fmaf(y1,y1, z1*z1)));
            q2 = make_float4(x2, y2, z2, fmaf(x2,x2, fmaf(y2,y2, z2*z2)));
        }
        pw1[tid] = q1; pw2[tid] = q2;
    }

    if (tid < B_ * OPP7_) {
        int b = tid / OPP7_, n = tid - b * OPP7_;
        float4 q1 = make_float4(0.f, 0.f, 0.f, 1e30f), q2 = q1;
        if (n < N_) {
            float x1 = v1[(b*N_+n)*3+0], y1 = v1[(b*N_+n)*3+1], z1 = v1[(b*N_+n)*3+2];
            float x2 = v2[(b*N_+n)*3+0], y2 = v2[(b*N_+n)*3+1], z2 = v2[(b*N_+n)*3+2];
            q1 = make_float4(-2.f*x1, -2.f*y1, -2.f*z1, fmaf(x1,x1, fmaf(y1,y1, z1*z1)));
            q2 = make_float4(-2.f*x2, -2.f*y2, -2.f*z2, fmaf(x2,x2, fmaf(y2,y2, z2*z2)));
        }
        st1[tid] = q1; st2[tid] = q2;
    }

    if (tid < 2 * B_ * NFP_) {
        int src = tid >> 12;
        int rr  = tid & (B_ * NFP_ - 1);
        int b   = rr >> 11;
        int f   = rr & (NFP_ - 1);
        const float* V = src ? v2 : v1;
        float Ax=1.f,Ay=1.f,Az=1.f,Bx=1.f,By=1.f,Bz=1.f,Cx=1.f,Cy=1.f,Cz=1.f;
        if (f < NF_) {
            int i0 = faces[f*3+0], i1 = faces[f*3+1], i2 = faces[f*3+2];
            Ax=V[(b*N_+i0)*3+0]; Ay=V[(b*N_+i0)*3+1]; Az=V[(b*N_+i0)*3+2];
            Bx=V[(b*N_+i1)*3+0]; By=V[(b*N_+i1)*3+1]; Bz=V[(b*N_+i1)*3+2];
            Cx=V[(b*N_+i2)*3+0]; Cy=V[(b*N_+i2)*3+1]; Cz=V[(b*N_+i2)*3+2];
        }
        float Sx = (Ay*Bz - Az*By) + (By*Cz - Bz*Cy) + (Cy*Az - Cz*Ay);
        float Sy = (Az*Bx - Ax*Bz) + (Bz*Cx - Bx*Cz) + (Cz*Ax - Cx*Az);
        float Sz = (Ax*By - Ay*Bx) + (Bx*Cy - By*Cx) + (Cx*Ay - Cy*Ax);
        float det0 = Ax*(By*Cz - Bz*Cy) + Ay*(Bz*Cx - Bx*Cz) + Az*(Bx*Cy - By*Cx);
        float na = Ax*Ax+Ay*Ay+Az*Az, nb = Bx*Bx+By*By+Bz*Bz, nc = Cx*Cx+Cy*Cy+Cz*Cz;
        float qab = Ax*Bx+Ay*By+Az*Bz, qbc = Bx*Cx+By*Cy+Bz*Cz, qca = Cx*Ax+Cy*Ay+Cz*Az;
        float* o = (src ? tbl2 : tbl1) + ((b << 11) + f) * 20;
        o[0]=Ax;  o[1]=Ay;  o[2]=Az;  o[3]=Bx;  o[4]=By;  o[5]=Bz;
        o[6]=Cx;  o[7]=Cy;  o[8]=Cz;  o[9]=-Sx; o[10]=-Sy; o[11]=-Sz;
        o[12]=det0; o[13]=na; o[14]=nb; o[15]=nc;
        o[16]=qab;  o[17]=qbc; o[18]=qca; o[19]=0.f;
    }
}

// per-record solid-angle/2pi given point P(x,y,z) and s=|p|^2 in scope
#define ANG(u0,u1,u2,u3,u4) ({                                               \
    float dAp = fmaf(u0.x,P.x, fmaf(u0.y,P.y, u0.z*P.z));                    \
    float dBp = fmaf(u0.w,P.x, fmaf(u1.x,P.y, u1.y*P.z));                    \
    float dCp = fmaf(u1.z,P.x, fmaf(u1.w,P.y, u2.x*P.z));                    \
    float det = fmaf(u2.y,P.x, fmaf(u2.z,P.y, fmaf(u2.w,P.z, u3.x)));        \
    float la = __builtin_amdgcn_sqrtf(fmaxf(fmaf(-2.f,dAp,u3.y+s),0.f));     \
    float lb = __builtin_amdgcn_sqrtf(fmaxf(fmaf(-2.f,dBp,u3.z+s),0.f));     \
    float lc = __builtin_amdgcn_sqrtf(fmaxf(fmaf(-2.f,dCp,u3.w+s),0.f));     \
    float dab = (u4.x+s)-(dAp+dBp);                                          \
    float dbc = (u4.y+s)-(dBp+dCp);                                          \
    float dca = (u4.z+s)-(dCp+dAp);                                          \
    float denom = fmaf(fmaf(la,lb,dab),lc, fmaf(dbc,la,dca*lb));             \
    atan2_o2pi(det, denom); })

// ---------------------------------------------------------------------------
// mega (persistent, atomic-slot version):
//   - per-wave point slice DUPLICATED in LDS -> ds_read_b128 with immediate
//     offsets (zero per-iter address math, prefetchable)
//   - no register rotation: winding accumulates via ds_add_f32 into per-point
//     LDS slots; rowmin via ds_min on float bits (values >= 0).
//     Each slot is touched by exactly one wave, one op per iteration, in
//     program order -> deterministic.
// ---------------------------------------------------------------------------
__global__ __launch_bounds__(256) void mega_kernel(
        const float4* __restrict__ pw1, const float4* __restrict__ pw2,
        const float* __restrict__ tbl1, const float* __restrict__ tbl2,
        const float4* __restrict__ st1, const float4* __restrict__ st2,
        float* __restrict__ part, float* __restrict__ rmp) {
    __shared__ float4 ptsd[512];    // 4 waves x (64 pts duplicated) = 8 KB
    __shared__ float  slots[256];   // per-point accumulators / mins, 1 KB
    int t = threadIdx.x, wid = t >> 6, lane = t & 63;
    int pbase = (wid << 7) + lane;  // doubled-slice base
    int sbase = (wid << 6);

    for (int tile = blockIdx.x; tile < NTILE_; tile += GRID_) {
        int g = tile / 23, o = tile - g * 23;
        __syncthreads();   // protect LDS reuse across tiles

        if (o < TCG_) {
            // ---------------- winding ----------------
            int wb   = g * TCG_ + o;              // [0, 1728)
            int pgrp = wb % 27;
            int r    = wb / 27;                   // [0, 64)
            int cg   = r & 15, db = r >> 4;
            int b = db & 1, dir = db >> 1;

            const float4* pw  = dir ? pw2 : pw1;
            const float*  tbl = dir ? tbl1 : tbl2;

            float4 P0 = pw[b * NPT_ + pgrp * 256 + t];
            ptsd[pbase]      = P0;
            ptsd[pbase + 64] = P0;
            slots[t] = 0.f;

#define LREC(nm, j)                                                          \
            const float4* rp##nm = (const float4*)(tbl + (size_t)(b*NFP_ + cg*128 + j*64 + lane)*20); \
            float4 nm##0 = rp##nm[0], nm##1 = rp##nm[1], nm##2 = rp##nm[2],  \
                   nm##3 = rp##nm[3], nm##4 = rp##nm[4];
            LREC(A, 0) LREC(Bq, 1)
#undef LREC
            __syncthreads();

            const float4* mypts = ptsd + pbase;
            #pragma unroll 4
            for (int k = 0; k < 64; ++k) {
                float4 P = mypts[k];              // base + immediate offset
                float s = P.w;
                float g0 = ANG(A0,A1,A2,A3,A4);
                float g1 = ANG(Bq0,Bq1,Bq2,Bq3,Bq4);
                atomicAdd(&slots[sbase + ((lane + k) & 63)], g0 + g1);
            }
            __syncthreads();
            part[(db*TCG_ + cg)*NPT_ + pgrp*256 + t] = slots[t];
        } else {
            // ---------------- rowmin ----------------
            int rb   = g * OCG_ + (o - TCG_);     // [0, 756)
            int pgrp = rb % 27;
            int r    = rb / 27;                   // [0, 28)
            int ocg  = r % OCG_, db = r / OCG_;
            int b = db & 1, dir = db >> 1;

            const float4* pw = dir ? pw2 : pw1;
            const float4* st = dir ? st1 : st2;

            float4 P0 = pw[b * NPT_ + pgrp * 256 + t];
            ptsd[pbase]      = P0;
            ptsd[pbase + 64] = P0;
            slots[t] = 3.4e38f;

            const float4* qb = st + b * OPP7_ + ocg * 1024;
#define LQ(j) float4 q##j = qb[j*64 + lane];
            LQ(0) LQ(1) LQ(2) LQ(3) LQ(4) LQ(5) LQ(6) LQ(7)
            LQ(8) LQ(9) LQ(10) LQ(11) LQ(12) LQ(13) LQ(14) LQ(15)
#undef LQ
            __syncthreads();

            const float4* mypts = ptsd + pbase;
            #pragma unroll 2
            for (int k = 0; k < 64; ++k) {
                float4 P = mypts[k];
                float s = P.w;
#define DD(j) float d##j = fmaf(q##j.x,P.x, fmaf(q##j.y,P.y, fmaf(q##j.z,P.z, q##j.w)));
                DD(0) DD(1) DD(2) DD(3) DD(4) DD(5) DD(6) DD(7)
                DD(8) DD(9) DD(10) DD(11) DD(12) DD(13) DD(14) DD(15)
#undef DD
                float e0 = fminf(d0,d1),  e1 = fminf(d2,d3),  e2 = fminf(d4,d5),  e3 = fminf(d6,d7);
                float e4 = fminf(d8,d9),  e5 = fminf(d10,d11), e6 = fminf(d12,d13), e7 = fminf(d14,d15);
                float f0 = fminf(e0,e1), f1 = fminf(e2,e3), f2 = fminf(e4,e5), f3 = fminf(e6,e7);
                float h  = fminf(fminf(f0,f1), fminf(f2,f3));
                float d  = fmaxf(h + s, 0.f);      // squared distance >= 0
                atomicMin((int*)slots + (sbase + ((lane + k) & 63)),
                          __float_as_int(d));      // int-min == float-min for >=0
            }
            __syncthreads();
            rmp[(db*OCG_ + ocg)*NPT_ + pgrp*256 + t] = slots[t];
        }
    }
}

// ---------------------------------------------------------------------------
// fold: per (db, 256-point group): sum 16 winding partials, min 7 rowmin
// partials, block-reduce masked stats -> pstat[db*27+pg].
// ---------------------------------------------------------------------------
__global__ __launch_bounds__(256) void fold_kernel(
        const float* __restrict__ part, const float* __restrict__ rmp,
        float4* __restrict__ pstat) {
    int pg = blockIdx.x % 27, db = blockIdx.x / 27;
    int t = threadIdx.x, n = pg * 256 + t;

    float ws = 0.f;
    #pragma unroll
    for (int g = 0; g < TCG_; ++g) ws += part[(db*TCG_ + g)*NPT_ + n];
    float rv = 3.4e38f;
    #pragma unroll
    for (int g = 0; g < OCG_; ++g) rv = fminf(rv, rmp[(db*OCG_ + g)*NPT_ + n]);

    bool valid = n < N_;
    float d = sqrtf(rv);
    bool msk = valid && (ws >= 0.99f);
    float v_min = valid ? d : 3.4e38f;
    float v_max = msk ? d : -3.4e38f;
    float v_sum = msk ? d : 0.f;
    float v_cnt = msk ? 1.f : 0.f;

    #pragma unroll
    for (int off = 32; off; off >>= 1) {
        v_min = fminf(v_min, __shfl_down(v_min, off, 64));
        v_max = fmaxf(v_max, __shfl_down(v_max, off, 64));
        v_sum += __shfl_down(v_sum, off, 64);
        v_cnt += __shfl_down(v_cnt, off, 64);
    }
    __shared__ float4 sred[4];
    int wid = t >> 6, lane = t & 63;
    if (lane == 0) sred[wid] = make_float4(v_min, v_max, v_sum, v_cnt);
    __syncthreads();
    if (t == 0) {
        float4 a = sred[0], bb = sred[1], c = sred[2], dd = sred[3];
        pstat[db*27 + pg] = make_float4(
            fminf(fminf(a.x, bb.x), fminf(c.x, dd.x)),
            fmaxf(fmaxf(a.y, bb.y), fmaxf(c.y, dd.y)),
            (a.z + bb.z) + (c.z + dd.z),
            (a.w + bb.w) + (c.w + dd.w));
    }
}

// ---------------------------------------------------------------------------
// final: 1 block, wave w reduces db=w's 27 group stats; thread 0 writes [5][B].
// ---------------------------------------------------------------------------
__global__ void final_kernel(const float4* __restrict__ pstat, float* __restrict__ out) {
    int t = threadIdx.x, wid = t >> 6, lane = t & 63;    // wid = db
    float4 v = make_float4(3.4e38f, -3.4e38f, 0.f, 0.f);
    if (lane < 27) v = pstat[wid*27 + lane];
    #pragma unroll
    for (int off = 32; off; off >>= 1) {
        v.x = fminf(v.x, __shfl_down(v.x, off, 64));
        v.y = fmaxf(v.y, __shfl_down(v.y, off, 64));
        v.z += __shfl_down(v.z, off, 64);
        v.w += __shfl_down(v.w, off, 64);
    }
    __shared__ float4 res[4];
    if (lane == 0) res[wid] = v;
    __syncthreads();
    if (t == 0) {
        #pragma unroll
        for (int b = 0; b < B_; ++b) {
            float4 s1 = res[b], s2 = res[2 + b];
            out[0 + b] = s1.x;
            out[2 + b] = (s1.w > 0.f) ? s1.y : 0.f;
            out[4 + b] = (s1.w > 0.f) ? (s1.z / s1.w) : 0.f;
            out[6 + b] = (s2.w > 0.f) ? s2.y : 0.f;
            out[8 + b] = (s2.w > 0.f) ? (s2.z / s2.w) : 0.f;
        }
    }
}

extern "C" void kernel_launch(void* const* d_in, const int* in_sizes, int n_in,
                              void* d_out, int out_size, void* d_ws, size_t ws_size,
                              hipStream_t stream) {
    const float* v1    = (const float*)d_in[0];
    const float* v2    = (const float*)d_in[1];
    const int*   faces = (const int*)d_in[2];

    float4* f4 = (float4*)d_ws;
    float4* pw1   = f4;                         // B*NPT_  = 13824 f4
    float4* pw2   = pw1 + B_ * NPT_;
    float4* st1   = pw2 + B_ * NPT_;            // B*OPP7_ = 14336 f4
    float4* st2   = st1 + B_ * OPP7_;
    float4* pstat = st2 + B_ * OPP7_;           // 108 f4
    float*  tbl1  = (float*)(pstat + 128);      // B*NFP_*20 = 81920 f
    float*  tbl2  = tbl1 + B_ * NFP_ * 20;
    float*  part  = tbl2 + B_ * NFP_ * 20;      // 4*TCG_*NPT_ = 442368 f
    float*  rmp   = part + 4 * TCG_ * NPT_;     // 4*OCG_*NPT_ = 193536 f
                                                // total ~4.1 MB

    float* out = (float*)d_out;

    prep_kernel<<<(B_ * OPP7_ + 255) / 256, 256, 0, stream>>>(
        v1, v2, faces, pw1, pw2, st1, st2, tbl1, tbl2);

    mega_kernel<<<GRID_, 256, 0, stream>>>(
        pw1, pw2, tbl1, tbl2, st1, st2, part, rmp);

    fold_kernel<<<4 * 27, 256, 0, stream>>>(part, rmp, pstat);

    final_kernel<<<1, 256, 0, stream>>>(pstat, out);
}

// Round 11
// 107.704 us; speedup vs baseline: 1.8286x; 1.8286x over previous
//
#include <hip/hip_runtime.h>
#include <math.h>

#define B_     2
#define N_     6890
#define NF_    2000
#define NFP_   2048     // padded triangles: 16 chunks x 128
#define NPT_   6912     // padded points: 27*256
#define OPP7_  7168     // padded opposite cloud: 7 chunks x 1024
#define TCG_   16       // tri chunks (128 tris each, 2 recs/lane)
#define OCG_   7        // opp chunks (1024 recs each, 16 recs/lane)
#define NTILE_ (4 * (TCG_ + OCG_) * 27)   // 2484 logical tiles (23-interleaved)
#define GRID_  2048                        // persistent

typedef float v2f __attribute__((ext_vector_type(2)));
#define VFMA(a,b,c) __builtin_elementwise_fma((v2f)(a), (v2f)(b), (v2f)(c))

// ---------------------------------------------------------------------------
// atan2(y,x)/(2*pi): branchless octant reduction, single rcp, scale folded in.
// ---------------------------------------------------------------------------
__device__ __forceinline__ float atan2_o2pi(float y, float x) {
    float ax = __builtin_fabsf(x);
    float ay = __builtin_fabsf(y);
    float mx = fmaxf(ax, ay);
    float mn = fminf(ax, ay);
    bool  big = mn > 0.41421356f * mx;
    float num = big ? (mn - mx) : mn;
    float den = big ? (mn + mx) : mx;
    float t   = num * __builtin_amdgcn_rcpf(den);
    float z   = t * t;
    float p   = fmaf(fmaf(fmaf(1.2817932e-2f, z, -2.2087019e-2f), z,
                          3.1795514e-2f), z, -5.3051037e-2f);   // coeffs / 2pi
    float r   = fmaf(t, fmaf(z, p, 0.15915494309f), big ? 0.125f : 0.0f);
    r = (ay > ax)  ? 0.25f - r : r;
    r = (x < 0.0f) ? 0.5f  - r : r;
    return copysignf(r, y);
}

// ---------------------------------------------------------------------------
// prep (layouts unchanged):
//  pw[b][n] = (x,y,z,|p|^2)        pad zeros              [B][NPT_]
//  st[b][n] = (-2x,-2y,-2z,|o|^2)  pad (0,0,0,1e30)       [B][OPP7_]
//  tbl[b][f][20] = [A,B,C, -S, det0, na,nb,nc, qab,qbc,qca, 0]
// ---------------------------------------------------------------------------
__global__ void prep_kernel(const float* __restrict__ v1, const float* __restrict__ v2,
                            const int* __restrict__ faces,
                            float4* __restrict__ pw1, float4* __restrict__ pw2,
                            float4* __restrict__ st1, float4* __restrict__ st2,
                            float* __restrict__ tbl1, float* __restrict__ tbl2) {
    int tid = blockIdx.x * 256 + threadIdx.x;

    if (tid < B_ * NPT_) {
        int b = tid / NPT_, n = tid - b * NPT_;
        float4 q1 = make_float4(0.f, 0.f, 0.f, 0.f), q2 = q1;
        if (n < N_) {
            float x1 = v1[(b*N_+n)*3+0], y1 = v1[(b*N_+n)*3+1], z1 = v1[(b*N_+n)*3+2];
            float x2 = v2[(b*N_+n)*3+0], y2 = v2[(b*N_+n)*3+1], z2 = v2[(b*N_+n)*3+2];
            q1 = make_float4(x1, y1, z1, fmaf(x1,x1, fmaf(y1,y1, z1*z1)));
            q2 = make_float4(x2, y2, z2, fmaf(x2,x2, fmaf(y2,y2, z2*z2)));
        }
        pw1[tid] = q1; pw2[tid] = q2;
    }

    if (tid < B_ * OPP7_) {
        int b = tid / OPP7_, n = tid - b * OPP7_;
        float4 q1 = make_float4(0.f, 0.f, 0.f, 1e30f), q2 = q1;
        if (n < N_) {
            float x1 = v1[(b*N_+n)*3+0], y1 = v1[(b*N_+n)*3+1], z1 = v1[(b*N_+n)*3+2];
            float x2 = v2[(b*N_+n)*3+0], y2 = v2[(b*N_+n)*3+1], z2 = v2[(b*N_+n)*3+2];
            q1 = make_float4(-2.f*x1, -2.f*y1, -2.f*z1, fmaf(x1,x1, fmaf(y1,y1, z1*z1)));
            q2 = make_float4(-2.f*x2, -2.f*y2, -2.f*z2, fmaf(x2,x2, fmaf(y2,y2, z2*z2)));
        }
        st1[tid] = q1; st2[tid] = q2;
    }

    if (tid < 2 * B_ * NFP_) {
        int src = tid >> 12;
        int rr  = tid & (B_ * NFP_ - 1);
        int b   = rr >> 11;
        int f   = rr & (NFP_ - 1);
        const float* V = src ? v2 : v1;
        float Ax=1.f,Ay=1.f,Az=1.f,Bx=1.f,By=1.f,Bz=1.f,Cx=1.f,Cy=1.f,Cz=1.f;
        if (f < NF_) {
            int i0 = faces[f*3+0], i1 = faces[f*3+1], i2 = faces[f*3+2];
            Ax=V[(b*N_+i0)*3+0]; Ay=V[(b*N_+i0)*3+1]; Az=V[(b*N_+i0)*3+2];
            Bx=V[(b*N_+i1)*3+0]; By=V[(b*N_+i1)*3+1]; Bz=V[(b*N_+i1)*3+2];
            Cx=V[(b*N_+i2)*3+0]; Cy=V[(b*N_+i2)*3+1]; Cz=V[(b*N_+i2)*3+2];
        }
        float Sx = (Ay*Bz - Az*By) + (By*Cz - Bz*Cy) + (Cy*Az - Cz*Ay);
        float Sy = (Az*Bx - Ax*Bz) + (Bz*Cx - Bx*Cz) + (Cz*Ax - Cx*Az);
        float Sz = (Ax*By - Ay*Bx) + (Bx*Cy - By*Cx) + (Cx*Ay - Cy*Ax);
        float det0 = Ax*(By*Cz - Bz*Cy) + Ay*(Bz*Cx - Bx*Cz) + Az*(Bx*Cy - By*Cx);
        float na = Ax*Ax+Ay*Ay+Az*Az, nb = Bx*Bx+By*By+Bz*Bz, nc = Cx*Cx+Cy*Cy+Cz*Cz;
        float qab = Ax*Bx+Ay*By+Az*Bz, qbc = Bx*Cx+By*Cy+Bz*Cz, qca = Cx*Ax+Cy*Ay+Cz*Az;
        float* o = (src ? tbl2 : tbl1) + ((b << 11) + f) * 20;
        o[0]=Ax;  o[1]=Ay;  o[2]=Az;  o[3]=Bx;  o[4]=By;  o[5]=Bz;
        o[6]=Cx;  o[7]=Cy;  o[8]=Cz;  o[9]=-Sx; o[10]=-Sy; o[11]=-Sz;
        o[12]=det0; o[13]=na; o[14]=nb; o[15]=nc;
        o[16]=qab;  o[17]=qbc; o[18]=qca; o[19]=0.f;
    }
}

// ---------------------------------------------------------------------------
// mega (persistent): winding ANG math packed across the lane's TWO triangle
// records via <2 x float> (v_pk_fma_f32 path on gfx950); atan2 scalar x2
// (independent chains -> ILP). Points duplicated in LDS -> ds_read_b128 with
// immediate offsets. Accumulator rotation via shfl (NOT atomics - r10 lesson).
// ---------------------------------------------------------------------------
__global__ __launch_bounds__(256) void mega_kernel(
        const float4* __restrict__ pw1, const float4* __restrict__ pw2,
        const float* __restrict__ tbl1, const float* __restrict__ tbl2,
        const float4* __restrict__ st1, const float4* __restrict__ st2,
        float* __restrict__ part, float* __restrict__ rmp) {
    __shared__ float4 ptsd[512];    // 4 waves x (64 pts duplicated) = 8 KB
    int t = threadIdx.x, wid = t >> 6, lane = t & 63;
    int pbase = (wid << 7) + lane;  // doubled-slice base
    int srcl = (lane + 1) & 63;

    for (int tile = blockIdx.x; tile < NTILE_; tile += GRID_) {
        int g = tile / 23, o = tile - g * 23;
        __syncthreads();   // protect LDS reuse across tiles

        if (o < TCG_) {
            // ---------------- winding ----------------
            int wb   = g * TCG_ + o;              // [0, 1728)
            int pgrp = wb % 27;
            int r    = wb / 27;                   // [0, 64)
            int cg   = r & 15, db = r >> 4;
            int b = db & 1, dir = db >> 1;

            const float4* pw  = dir ? pw2 : pw1;
            const float*  tbl = dir ? tbl1 : tbl2;

            float4 P0 = pw[b * NPT_ + pgrp * 256 + t];
            ptsd[pbase]      = P0;
            ptsd[pbase + 64] = P0;

            const float4* rpA = (const float4*)(tbl + (size_t)(b*NFP_ + cg*128 +   0 + lane)*20);
            const float4* rpB = (const float4*)(tbl + (size_t)(b*NFP_ + cg*128 +  64 + lane)*20);
            float4 a0 = rpA[0], a1 = rpA[1], a2 = rpA[2], a3 = rpA[3], a4 = rpA[4];
            float4 b0 = rpB[0], b1 = rpB[1], b2 = rpB[2], b3 = rpB[3], b4 = rpB[4];
            // pack the two records component-wise into v2f
            v2f cAx = {a0.x,b0.x}, cAy = {a0.y,b0.y}, cAz = {a0.z,b0.z};
            v2f cBx = {a0.w,b0.w}, cBy = {a1.x,b1.x}, cBz = {a1.y,b1.y};
            v2f cCx = {a1.z,b1.z}, cCy = {a1.w,b1.w}, cCz = {a2.x,b2.x};
            v2f cSx = {a2.y,b2.y}, cSy = {a2.z,b2.z}, cSz = {a2.w,b2.w};
            v2f cD0 = {a3.x,b3.x}, cNa = {a3.y,b3.y}, cNb = {a3.z,b3.z}, cNc = {a3.w,b3.w};
            v2f cQab= {a4.x,b4.x}, cQbc= {a4.y,b4.y}, cQca= {a4.z,b4.z};
            __syncthreads();

            const float4* mypts = ptsd + pbase;
            float acc = 0.f;
            #pragma unroll 4
            for (int k = 0; k < 64; ++k) {
                float4 P = mypts[k];              // base + immediate offset
                v2f px = P.x, py = P.y, pz = P.z, sv = P.w;
                v2f dAp = VFMA(cAx, px, VFMA(cAy, py, cAz * pz));
                v2f dBp = VFMA(cBx, px, VFMA(cBy, py, cBz * pz));
                v2f dCp = VFMA(cCx, px, VFMA(cCy, py, cCz * pz));
                v2f det = VFMA(cSx, px, VFMA(cSy, py, VFMA(cSz, pz, cD0)));
                v2f la2 = VFMA((v2f)(-2.f), dAp, cNa + sv);
                v2f lb2 = VFMA((v2f)(-2.f), dBp, cNb + sv);
                v2f lc2 = VFMA((v2f)(-2.f), dCp, cNc + sv);
                v2f la, lb, lc;
                la.x = __builtin_amdgcn_sqrtf(fmaxf(la2.x, 0.f));
                la.y = __builtin_amdgcn_sqrtf(fmaxf(la2.y, 0.f));
                lb.x = __builtin_amdgcn_sqrtf(fmaxf(lb2.x, 0.f));
                lb.y = __builtin_amdgcn_sqrtf(fmaxf(lb2.y, 0.f));
                lc.x = __builtin_amdgcn_sqrtf(fmaxf(lc2.x, 0.f));
                lc.y = __builtin_amdgcn_sqrtf(fmaxf(lc2.y, 0.f));
                v2f dab = (cQab + sv) - (dAp + dBp);
                v2f dbc = (cQbc + sv) - (dBp + dCp);
                v2f dca = (cQca + sv) - (dCp + dAp);
                v2f denom = VFMA(VFMA(la, lb, dab), lc, VFMA(dbc, la, dca * lb));
                float g0 = atan2_o2pi(det.x, denom.x);
                float g1 = atan2_o2pi(det.y, denom.y);
                acc += g0 + g1;
                acc = __shfl(acc, srcl, 64);
            }
            part[(db*TCG_ + cg)*NPT_ + pgrp*256 + t] = acc;
        } else {
            // ---------------- rowmin (r9 structure + dup-LDS read) ----------
            int rb   = g * OCG_ + (o - TCG_);     // [0, 756)
            int pgrp = rb % 27;
            int r    = rb / 27;                   // [0, 28)
            int ocg  = r % OCG_, db = r / OCG_;
            int b = db & 1, dir = db >> 1;

            const float4* pw = dir ? pw2 : pw1;
            const float4* st = dir ? st1 : st2;

            float4 P0 = pw[b * NPT_ + pgrp * 256 + t];
            ptsd[pbase]      = P0;
            ptsd[pbase + 64] = P0;

            const float4* qb = st + b * OPP7_ + ocg * 1024;
#define LQ(j) float4 q##j = qb[j*64 + lane];
            LQ(0) LQ(1) LQ(2) LQ(3) LQ(4) LQ(5) LQ(6) LQ(7)
            LQ(8) LQ(9) LQ(10) LQ(11) LQ(12) LQ(13) LQ(14) LQ(15)
#undef LQ
            __syncthreads();

            const float4* mypts = ptsd + pbase;
            float m = 3.4e38f;
            #pragma unroll 2
            for (int k = 0; k < 64; ++k) {
                float4 P = mypts[k];
                float s = P.w;
#define DD(j) float d##j = fmaf(q##j.x,P.x, fmaf(q##j.y,P.y, fmaf(q##j.z,P.z, q##j.w)));
                DD(0) DD(1) DD(2) DD(3) DD(4) DD(5) DD(6) DD(7)
                DD(8) DD(9) DD(10) DD(11) DD(12) DD(13) DD(14) DD(15)
#undef DD
                float e0 = fminf(d0,d1),  e1 = fminf(d2,d3),  e2 = fminf(d4,d5),  e3 = fminf(d6,d7);
                float e4 = fminf(d8,d9),  e5 = fminf(d10,d11), e6 = fminf(d12,d13), e7 = fminf(d14,d15);
                float f0 = fminf(e0,e1), f1 = fminf(e2,e3), f2 = fminf(e4,e5), f3 = fminf(e6,e7);
                float h  = fminf(fminf(f0,f1), fminf(f2,f3));
                m = fminf(m, h + s);               // |p|^2 hoisted out of fmas
                m = __shfl(m, srcl, 64);
            }
            rmp[(db*OCG_ + ocg)*NPT_ + pgrp*256 + t] = m;
        }
    }
}

// ---------------------------------------------------------------------------
// fold: per (db, 256-point group): sum 16 winding partials, min 7 rowmin
// partials, block-reduce masked stats -> pstat[db*27+pg].
// ---------------------------------------------------------------------------
__global__ __launch_bounds__(256) void fold_kernel(
        const float* __restrict__ part, const float* __restrict__ rmp,
        float4* __restrict__ pstat) {
    int pg = blockIdx.x % 27, db = blockIdx.x / 27;
    int t = threadIdx.x, n = pg * 256 + t;

    float ws = 0.f;
    #pragma unroll
    for (int g = 0; g < TCG_; ++g) ws += part[(db*TCG_ + g)*NPT_ + n];
    float rv = 3.4e38f;
    #pragma unroll
    for (int g = 0; g < OCG_; ++g) rv = fminf(rv, rmp[(db*OCG_ + g)*NPT_ + n]);

    bool valid = n < N_;
    float d = sqrtf(rv);
    bool msk = valid && (ws >= 0.99f);
    float v_min = valid ? d : 3.4e38f;
    float v_max = msk ? d : -3.4e38f;
    float v_sum = msk ? d : 0.f;
    float v_cnt = msk ? 1.f : 0.f;

    #pragma unroll
    for (int off = 32; off; off >>= 1) {
        v_min = fminf(v_min, __shfl_down(v_min, off, 64));
        v_max = fmaxf(v_max, __shfl_down(v_max, off, 64));
        v_sum += __shfl_down(v_sum, off, 64);
        v_cnt += __shfl_down(v_cnt, off, 64);
    }
    __shared__ float4 sred[4];
    int wid = t >> 6, lane = t & 63;
    if (lane == 0) sred[wid] = make_float4(v_min, v_max, v_sum, v_cnt);
    __syncthreads();
    if (t == 0) {
        float4 a = sred[0], bb = sred[1], c = sred[2], dd = sred[3];
        pstat[db*27 + pg] = make_float4(
            fminf(fminf(a.x, bb.x), fminf(c.x, dd.x)),
            fmaxf(fmaxf(a.y, bb.y), fmaxf(c.y, dd.y)),
            (a.z + bb.z) + (c.z + dd.z),
            (a.w + bb.w) + (c.w + dd.w));
    }
}

// ---------------------------------------------------------------------------
// final: 1 block, wave w reduces db=w's 27 group stats; thread 0 writes [5][B].
// ---------------------------------------------------------------------------
__global__ void final_kernel(const float4* __restrict__ pstat, float* __restrict__ out) {
    int t = threadIdx.x, wid = t >> 6, lane = t & 63;    // wid = db
    float4 v = make_float4(3.4e38f, -3.4e38f, 0.f, 0.f);
    if (lane < 27) v = pstat[wid*27 + lane];
    #pragma unroll
    for (int off = 32; off; off >>= 1) {
        v.x = fminf(v.x, __shfl_down(v.x, off, 64));
        v.y = fmaxf(v.y, __shfl_down(v.y, off, 64));
        v.z += __shfl_down(v.z, off, 64);
        v.w += __shfl_down(v.w, off, 64);
    }
    __shared__ float4 res[4];
    if (lane == 0) res[wid] = v;
    __syncthreads();
    if (t == 0) {
        #pragma unroll
        for (int b = 0; b < B_; ++b) {
            float4 s1 = res[b], s2 = res[2 + b];
            out[0 + b] = s1.x;
            out[2 + b] = (s1.w > 0.f) ? s1.y : 0.f;
            out[4 + b] = (s1.w > 0.f) ? (s1.z / s1.w) : 0.f;
            out[6 + b] = (s2.w > 0.f) ? s2.y : 0.f;
            out[8 + b] = (s2.w > 0.f) ? (s2.z / s2.w) : 0.f;
        }
    }
}

extern "C" void kernel_launch(void* const* d_in, const int* in_sizes, int n_in,
                              void* d_out, int out_size, void* d_ws, size_t ws_size,
                              hipStream_t stream) {
    const float* v1    = (const float*)d_in[0];
    const float* v2    = (const float*)d_in[1];
    const int*   faces = (const int*)d_in[2];

    float4* f4 = (float4*)d_ws;
    float4* pw1   = f4;                         // B*NPT_  = 13824 f4
    float4* pw2   = pw1 + B_ * NPT_;
    float4* st1   = pw2 + B_ * NPT_;            // B*OPP7_ = 14336 f4
    float4* st2   = st1 + B_ * OPP7_;
    float4* pstat = st2 + B_ * OPP7_;           // 108 f4
    float*  tbl1  = (float*)(pstat + 128);      // B*NFP_*20 = 81920 f
    float*  tbl2  = tbl1 + B_ * NFP_ * 20;
    float*  part  = tbl2 + B_ * NFP_ * 20;      // 4*TCG_*NPT_ = 442368 f
    float*  rmp   = part + 4 * TCG_ * NPT_;     // 4*OCG_*NPT_ = 193536 f
                                                // total ~4.1 MB

    float* out = (float*)d_out;

    prep_kernel<<<(B_ * OPP7_ + 255) / 256, 256, 0, stream>>>(
        v1, v2, faces, pw1, pw2, st1, st2, tbl1, tbl2);

    mega_kernel<<<GRID_, 256, 0, stream>>>(
        pw1, pw2, tbl1, tbl2, st1, st2, part, rmp);

    fold_kernel<<<4 * 27, 256, 0, stream>>>(part, rmp, pstat);

    final_kernel<<<1, 256, 0, stream>>>(pstat, out);
}